// Round 3
// baseline (3344.044 us; speedup 1.0000x reference)
//
#include <hip/hip_runtime.h>
#include <hip/hip_bf16.h>
#include <cstdint>

__device__ __forceinline__ float wave_sum(float v){
#pragma unroll
  for (int o = 32; o > 0; o >>= 1) v += __shfl_down(v, o, 64);
  return v;  // lane 0 holds the sum
}

// ---- copy f32 [n,64] -> f32 strided [n, stride] (block 0..63) ----
__global__ void k_copy_in(const float* __restrict__ src, float* __restrict__ dst,
                          int n, int stride){
  int idx = blockIdx.x * 256 + threadIdx.x;
  if (idx >= n * 64) return;
  int r = idx >> 6, j = idx & 63;
  dst[(size_t)r * stride + j] = src[idx];
}

// ---- fs[n,64] = x[n, xo:xo+64] @ W(64x64) + b ----
// block = 256 threads (4 waves), 16 nodes per block, W staged to LDS
__global__ void k_linear(const float* __restrict__ x, int xs, int xo,
                         const float* __restrict__ W, const float* __restrict__ b,
                         float* __restrict__ out, int n){
  __shared__ float Wf[64 * 64];
  __shared__ float xsh[16][64];
  int t = threadIdx.x;
  for (int i = t; i < 4096; i += 256) Wf[i] = W[i];
  int base = blockIdx.x * 16;
  for (int i = t; i < 16 * 64; i += 256){
    int r = i >> 6, j = i & 63;
    int nn = base + r;
    xsh[r][j] = (nn < n) ? x[(size_t)nn * xs + xo + j] : 0.f;
  }
  __syncthreads();
  int j = t & 63, w = t >> 6;
  float bj = b[j];
  for (int r = w; r < 16; r += 4){
    int nn = base + r;
    if (nn >= n) continue;
    float acc = bj;
#pragma unroll
    for (int k = 0; k < 64; ++k)
      acc += xsh[r][k] * Wf[k * 64 + j];
    out[(size_t)nn * 64 + j] = acc;
  }
}

// ---- pass 1: e = attn . lrelu(fs[s]+fd[d], 0.2); ex = exp(e); denom[d] += ex ----
// (|e| << 80 at these scales, so no max-subtraction needed: exp(e)/sum(exp(e))
//  is mathematically identical to the reference's exp(e-m)/sum(exp(e-m)))
__global__ void k_edge_e(const int* __restrict__ src, const int* __restrict__ dst,
                         const float* __restrict__ fs, const float* __restrict__ fd,
                         const float* __restrict__ attn,
                         float* __restrict__ e_buf, float* __restrict__ denom, int E){
  int k = blockIdx.x * 4 + (threadIdx.x >> 6);
  if (k >= E) return;
  int j = threadIdx.x & 63;
  int s = src[k], d = dst[k];
  float v = fs[(size_t)s * 64 + j] + fd[(size_t)d * 64 + j];
  v = v > 0.f ? v : 0.2f * v;
  v *= attn[j];
  float sum = wave_sum(v);
  if (j == 0){
    float ex = expf(sum);
    e_buf[k] = ex;
    atomicAdd(denom + d, ex);
  }
}

// ---- pass 2: out[d] += (ex/denom[d]) * fs[s] ----
__global__ void k_edge_scatter(const int* __restrict__ src, const int* __restrict__ dst,
                               const float* __restrict__ fs, const float* __restrict__ e_buf,
                               const float* __restrict__ denom,
                               float* __restrict__ out, int os, int oo, int E){
  int k = blockIdx.x * 4 + (threadIdx.x >> 6);
  if (k >= E) return;
  int j = threadIdx.x & 63;
  int s = src[k], d = dst[k];
  float alpha = e_buf[k] / denom[d];
  atomicAdd(out + (size_t)d * os + oo + j, alpha * fs[(size_t)s * 64 + j]);
}

__global__ void k_zero_strided(float* __restrict__ out, int os, int oo, int n){
  int idx = blockIdx.x * 256 + threadIdx.x;
  if (idx >= n * 64) return;
  out[(size_t)(idx >> 6) * os + oo + (idx & 63)] = 0.f;
}

// out[n, oo:oo+64] += bias (+ res[n, ro:ro+64] if res != null)
__global__ void k_finalize(float* __restrict__ out, int os, int oo,
                           const float* __restrict__ bias,
                           const float* __restrict__ res, int rs, int ro, int n){
  int idx = blockIdx.x * 256 + threadIdx.x;
  if (idx >= n * 64) return;
  int r = idx >> 6, j = idx & 63;
  float v = out[(size_t)r * os + oo + j] + bias[j];
  if (res) v += res[(size_t)r * rs + ro + j];
  out[(size_t)r * os + oo + j] = v;
}

// ---- collapse attention-gate MLP: v = W1@W2 (per l,i), c = b1@W2 + b2 ----
__global__ void k_attvec(const float* __restrict__ W1, const float* __restrict__ b1,
                         const float* __restrict__ W2, const float* __restrict__ b2,
                         float* __restrict__ vvec, float* __restrict__ cs){
  int t = threadIdx.x;           // 512 threads: (l*2+i) in [0,4), r in [0,128)
  int li = t >> 7, r = t & 127;
  float acc = 0.f;
  for (int c = 0; c < 128; ++c)
    acc += W1[(size_t)(li * 128 + r) * 128 + c] * W2[li * 128 + c];
  vvec[li * 128 + r] = acc;
  if (r == 0){
    float cacc = b2[li];
    for (int c = 0; c < 128; ++c)
      cacc += b1[li * 128 + c] * W2[li * 128 + c];
    cs[li] = cacc;
  }
}

// ---- gate z-scores + per-block partial sums for BatchNorm ----
__global__ void k_gate_z(const float* __restrict__ hu_all, int l,
                         const float* __restrict__ p, const float* __restrict__ q,
                         const float* __restrict__ vvec, const float* __restrict__ cs,
                         float* __restrict__ z1, float* __restrict__ z2,
                         float* __restrict__ bsums, int n){
  __shared__ float part[4][4];
  int w = threadIdx.x >> 6, j = threadIdx.x & 63;
  int nidx = blockIdx.x * 4 + w;
  float lz1 = 0.f, lz2 = 0.f;
  if (nidx < n){
    const float* v1 = vvec + l * 256;        // [l][0][128] (influence: p)
    const float* v2 = vvec + l * 256 + 128;  // [l][1][128] (interest:  q)
    float h  = hu_all[(size_t)nidx * 192 + l * 64 + j];
    float pv = p[(size_t)nidx * 64 + j];
    float qv = q[(size_t)nidx * 64 + j];
    float t1 = h * v1[j] + pv * v1[64 + j];
    float t2 = h * v2[j] + qv * v2[64 + j];
    t1 = wave_sum(t1);
    t2 = wave_sum(t2);
    if (j == 0){
      lz1 = t1 + cs[l * 2 + 0];
      lz2 = t2 + cs[l * 2 + 1];
      z1[nidx] = lz1;
      z2[nidx] = lz2;
    }
  }
  if (j == 0){
    part[w][0] = lz1; part[w][1] = lz1 * lz1;
    part[w][2] = lz2; part[w][3] = lz2 * lz2;
  }
  __syncthreads();
  if (threadIdx.x < 4)
    bsums[(size_t)blockIdx.x * 4 + threadIdx.x] =
        part[0][threadIdx.x] + part[1][threadIdx.x] +
        part[2][threadIdx.x] + part[3][threadIdx.x];
}

// ---- deterministic reduce of per-block partials -> sums[4] (f64) ----
__global__ void k_bn_reduce(const float* __restrict__ bsums, int nb,
                            double* __restrict__ sums){
  __shared__ double sh[256];
  int c = threadIdx.x & 3, chunk = threadIdx.x >> 2;   // 64 chunks x 4 components
  double acc = 0.0;
  for (int i = chunk; i < nb; i += 64) acc += (double)bsums[(size_t)i * 4 + c];
  sh[threadIdx.x] = acc;
  __syncthreads();
  for (int s = 128; s >= 4; s >>= 1){
    if (threadIdx.x < s) sh[threadIdx.x] += sh[threadIdx.x + s];
    __syncthreads();
  }
  if (threadIdx.x < 4) sums[threadIdx.x] = sh[threadIdx.x];
}

// ---- BN + lrelu(0.01) + softmax gate + residual combine -> hu_all block l+1 ----
__global__ void k_gate_combine(float* __restrict__ hu_all, int l,
                               const float* __restrict__ p, const float* __restrict__ q,
                               const float* __restrict__ z1, const float* __restrict__ z2,
                               const double* __restrict__ sums, int n){
  int idx = blockIdx.x * 256 + threadIdx.x;
  if (idx >= n * 64) return;
  int r = idx >> 6, j = idx & 63;
  double invn = 1.0 / (double)n;
  double mu1 = sums[0] * invn, mu2 = sums[2] * invn;
  float var1 = (float)(sums[1] * invn - mu1 * mu1);
  float var2 = (float)(sums[3] * invn - mu2 * mu2);
  float rs1 = rsqrtf(var1 + 1e-5f), rs2 = rsqrtf(var2 + 1e-5f);
  float a1 = (z1[r] - (float)mu1) * rs1;
  float a2 = (z2[r] - (float)mu2) * rs2;
  a1 = a1 > 0.f ? a1 : 0.01f * a1;
  a2 = a2 > 0.f ? a2 : 0.01f * a2;
  float mx = fmaxf(a1, a2);
  float e1 = __expf(a1 - mx), e2 = __expf(a2 - mx);
  float inv = 1.f / (e1 + e2);
  float g0 = e1 * inv, g1 = e2 * inv;
  float out = g0 * p[idx] + g1 * q[idx] + hu_all[(size_t)r * 192 + l * 64 + j];
  hu_all[(size_t)r * 192 + (l + 1) * 64 + j] = out;
}

// ---- final scoring: dot(hu_all[u], hi_all[i]) over 192 dims ----
__global__ void k_score(const int* __restrict__ pu, const int* __restrict__ pi,
                        const int* __restrict__ nu, const int* __restrict__ ni,
                        const float* __restrict__ hu_all, const float* __restrict__ hi_all,
                        float* __restrict__ out, int EP){
  int k = blockIdx.x * 4 + (threadIdx.x >> 6);
  if (k >= 2 * EP) return;
  int j = threadIdx.x & 63;
  int u, i;
  if (k < EP){ u = pu[k]; i = pi[k]; } else { u = nu[k - EP]; i = ni[k - EP]; }
  const float* hu = hu_all + (size_t)u * 192;
  const float* hi = hi_all + (size_t)i * 192;
  float acc = hu[j] * hi[j] + hu[j + 64] * hi[j + 64] + hu[j + 128] * hi[j + 128];
  acc = wave_sum(acc);
  if (j == 0) out[k] = acc;
}

extern "C" void kernel_launch(void* const* d_in, const int* in_sizes, int n_in,
                              void* d_out, int out_size, void* d_ws, size_t ws_size,
                              hipStream_t stream) {
  const int*   rate_src  = (const int*)  d_in[0];
  const int*   rate_dst  = (const int*)  d_in[1];
  const int*   trust_src = (const int*)  d_in[2];
  const int*   trust_dst = (const int*)  d_in[3];
  const int*   pos_u     = (const int*)  d_in[4];
  const int*   pos_i     = (const int*)  d_in[5];
  const int*   neg_u     = (const int*)  d_in[6];
  const int*   neg_i     = (const int*)  d_in[7];
  const float* eu        = (const float*)d_in[8];
  const float* ei        = (const float*)d_in[9];
  const float* rate_W    = (const float*)d_in[10];
  const float* rate_b    = (const float*)d_in[11];
  const float* rate_attn = (const float*)d_in[12];
  const float* rate_bias = (const float*)d_in[13];
  const float* rb_W      = (const float*)d_in[14];
  const float* rb_b      = (const float*)d_in[15];
  const float* rb_attn   = (const float*)d_in[16];
  const float* rb_bias   = (const float*)d_in[17];
  const float* tr_W      = (const float*)d_in[18];
  const float* tr_b      = (const float*)d_in[19];
  const float* tr_attn   = (const float*)d_in[20];
  const float* tr_bias   = (const float*)d_in[21];
  const float* attW1     = (const float*)d_in[22];
  const float* attb1     = (const float*)d_in[23];
  const float* attW2     = (const float*)d_in[24];
  const float* attb2     = (const float*)d_in[25];

  const int ER = in_sizes[0];
  const int ET = in_sizes[2];
  const int EP = in_sizes[4];
  const int NU = in_sizes[8] / 64;
  const int NI = in_sizes[9] / 64;

  // ---- workspace layout (f32), ~224 MiB total ----
  float* ws = (float*)d_ws;
  float*  hu_all = ws;                                   // NU*192
  float*  hi_all = hu_all + (size_t)NU * 192;            // NI*192
  float*  p      = hi_all + (size_t)NI * 192;            // NU*64
  float*  q      = p + (size_t)NU * 64;                  // NU*64
  float*  fs     = q + (size_t)NU * 64;                  // NU*64
  float*  fd     = fs + (size_t)NU * 64;                 // NU*64
  float*  e_buf  = fd + (size_t)NU * 64;                 // ER
  float*  denom  = e_buf + ER;                           // NU
  float*  z1     = denom + NU;                           // NU
  float*  z2     = z1 + NU;                              // NU
  float*  bsums  = z2 + NU;                              // cdiv(NU,4)*4
  float*  vvec   = bsums + (size_t)(((NU + 3) / 4) * 4); // 512
  float*  cs     = vvec + 512;                           // 4
  double* sums   = (double*)(((uintptr_t)(cs + 4) + 15) & ~(uintptr_t)15); // 4

  auto cdiv = [](int a, int b){ return (a + b - 1) / b; };
  const int nbz = cdiv(NU, 4);   // k_gate_z block count

  // init: eu/ei -> block 0 of hu_all/hi_all; collapse gate MLP
  k_copy_in<<<cdiv(NU * 64, 256), 256, 0, stream>>>(eu, hu_all, NU, 192);
  k_copy_in<<<cdiv(NI * 64, 256), 256, 0, stream>>>(ei, hi_all, NI, 192);
  k_attvec<<<1, 512, 0, stream>>>(attW1, attb1, attW2, attb2, vvec, cs);

  for (int l = 0; l < 2; ++l){
    // ---------- rate GAT: users -> items, result into hi_all block l+1 ----------
    k_linear<<<cdiv(NU, 16), 256, 0, stream>>>(hu_all, 192, l * 64,
        rate_W + (size_t)(l * 2 + 0) * 4096, rate_b + (l * 2 + 0) * 64, fs, NU);
    k_linear<<<cdiv(NI, 16), 256, 0, stream>>>(hi_all, 192, l * 64,
        rate_W + (size_t)(l * 2 + 1) * 4096, rate_b + (l * 2 + 1) * 64, fd, NI);
    hipMemsetAsync(denom, 0, (size_t)NU * 4, stream);
    k_edge_e<<<cdiv(ER, 4), 256, 0, stream>>>(rate_src, rate_dst, fs, fd,
        rate_attn + l * 64, e_buf, denom, ER);
    k_zero_strided<<<cdiv(NI * 64, 256), 256, 0, stream>>>(hi_all, 192, (l + 1) * 64, NI);
    k_edge_scatter<<<cdiv(ER, 4), 256, 0, stream>>>(rate_src, rate_dst, fs, e_buf,
        denom, hi_all, 192, (l + 1) * 64, ER);
    k_finalize<<<cdiv(NI * 64, 256), 256, 0, stream>>>(hi_all, 192, (l + 1) * 64,
        rate_bias + l * 64, hi_all, 192, l * 64, NI);  // + bias + old hi residual

    // ---------- rated-by GAT: items -> users, result q ----------
    k_linear<<<cdiv(NI, 16), 256, 0, stream>>>(hi_all, 192, l * 64,
        rb_W + (size_t)(l * 2 + 0) * 4096, rb_b + (l * 2 + 0) * 64, fs, NI);
    k_linear<<<cdiv(NU, 16), 256, 0, stream>>>(hu_all, 192, l * 64,
        rb_W + (size_t)(l * 2 + 1) * 4096, rb_b + (l * 2 + 1) * 64, fd, NU);
    hipMemsetAsync(denom, 0, (size_t)NU * 4, stream);
    k_edge_e<<<cdiv(ER, 4), 256, 0, stream>>>(rate_dst, rate_src, fs, fd,
        rb_attn + l * 64, e_buf, denom, ER);
    hipMemsetAsync(q, 0, (size_t)NU * 64 * 4, stream);
    k_edge_scatter<<<cdiv(ER, 4), 256, 0, stream>>>(rate_dst, rate_src, fs, e_buf,
        denom, q, 64, 0, ER);
    k_finalize<<<cdiv(NU * 64, 256), 256, 0, stream>>>(q, 64, 0,
        rb_bias + l * 64, (const float*)nullptr, 0, 0, NU);

    // ---------- trust GAT: users -> users, result p ----------
    k_linear<<<cdiv(NU, 16), 256, 0, stream>>>(hu_all, 192, l * 64,
        tr_W + (size_t)(l * 2 + 0) * 4096, tr_b + (l * 2 + 0) * 64, fs, NU);
    k_linear<<<cdiv(NU, 16), 256, 0, stream>>>(hu_all, 192, l * 64,
        tr_W + (size_t)(l * 2 + 1) * 4096, tr_b + (l * 2 + 1) * 64, fd, NU);
    hipMemsetAsync(denom, 0, (size_t)NU * 4, stream);
    k_edge_e<<<cdiv(ET, 4), 256, 0, stream>>>(trust_src, trust_dst, fs, fd,
        tr_attn + l * 64, e_buf, denom, ET);
    hipMemsetAsync(p, 0, (size_t)NU * 64 * 4, stream);
    k_edge_scatter<<<cdiv(ET, 4), 256, 0, stream>>>(trust_src, trust_dst, fs, e_buf,
        denom, p, 64, 0, ET);
    k_finalize<<<cdiv(NU * 64, 256), 256, 0, stream>>>(p, 64, 0,
        tr_bias + l * 64, (const float*)nullptr, 0, 0, NU);

    // ---------- attention gate + combine -> hu_all block l+1 ----------
    k_gate_z<<<nbz, 256, 0, stream>>>(hu_all, l, p, q, vvec, cs, z1, z2, bsums, NU);
    k_bn_reduce<<<1, 256, 0, stream>>>(bsums, nbz, sums);
    k_gate_combine<<<cdiv(NU * 64, 256), 256, 0, stream>>>(hu_all, l, p, q, z1, z2, sums, NU);
  }

  // ---------- final scoring ----------
  k_score<<<cdiv(2 * EP, 4), 256, 0, stream>>>(pos_u, pos_i, neg_u, neg_i,
      hu_all, hi_all, (float*)d_out, EP);
}

// Round 4
// 2270.346 us; speedup vs baseline: 1.4729x; 1.4729x over previous
//
#include <hip/hip_runtime.h>
#include <hip/hip_bf16.h>
#include <cstdint>

// butterfly: all lanes end with the full 64-lane sum
__device__ __forceinline__ float wave_sum_all(float v){
#pragma unroll
  for (int o = 32; o > 0; o >>= 1) v += __shfl_xor(v, o, 64);
  return v;
}
__device__ __forceinline__ float wave_sum(float v){
#pragma unroll
  for (int o = 32; o > 0; o >>= 1) v += __shfl_down(v, o, 64);
  return v;  // lane 0 holds the sum
}

// ---- copy f32 [n,64] -> f32 strided [n, stride] ----
__global__ void k_copy_in(const float* __restrict__ src, float* __restrict__ dst,
                          int n, int stride){
  int idx = blockIdx.x * 256 + threadIdx.x;
  if (idx >= n * 64) return;
  int r = idx >> 6, j = idx & 63;
  dst[(size_t)r * stride + j] = src[idx];
}

// ---- fs[n,64] = x[n, xo:xo+64] @ W(64x64) + b ----
__global__ void k_linear(const float* __restrict__ x, int xs, int xo,
                         const float* __restrict__ W, const float* __restrict__ b,
                         float* __restrict__ out, int n){
  __shared__ float Wf[64 * 64];
  __shared__ float xsh[16][64];
  int t = threadIdx.x;
  for (int i = t; i < 4096; i += 256) Wf[i] = W[i];
  int base = blockIdx.x * 16;
  for (int i = t; i < 16 * 64; i += 256){
    int r = i >> 6, j = i & 63;
    int nn = base + r;
    xsh[r][j] = (nn < n) ? x[(size_t)nn * xs + xo + j] : 0.f;
  }
  __syncthreads();
  int j = t & 63, w = t >> 6;
  float bj = b[j];
  for (int r = w; r < 16; r += 4){
    int nn = base + r;
    if (nn >= n) continue;
    float acc = bj;
#pragma unroll
    for (int k = 0; k < 64; ++k)
      acc += xsh[r][k] * Wf[k * 64 + j];
    out[(size_t)nn * 64 + j] = acc;
  }
}

// ================= CSR build (per call; ws is re-poisoned) =================
__global__ void k_hist(const int* __restrict__ dst, int* __restrict__ cnt, int E){
  int k = blockIdx.x * 256 + threadIdx.x;
  if (k < E) atomicAdd(cnt + dst[k], 1);
}

// single-block exclusive scan of cnt[0..n) -> offs[0..n], cur[0..n)
// 1024 threads = 16 waves; wave-shfl scan, 2 barriers per 1024-chunk
__global__ void k_scan(const int* __restrict__ cnt, int n,
                       int* __restrict__ offs, int* __restrict__ cur){
  __shared__ int wsum[16];
  __shared__ int base_sh;
  int t = threadIdx.x, lane = t & 63, w = t >> 6;
  if (t == 0) base_sh = 0;
  __syncthreads();
  for (int start = 0; start < n; start += 1024){
    int i = start + t;
    int v = (i < n) ? cnt[i] : 0;
    int x = v;                       // inclusive scan within wave
#pragma unroll
    for (int o = 1; o < 64; o <<= 1){
      int y = __shfl_up(x, o, 64);
      if (lane >= o) x += y;
    }
    if (lane == 63) wsum[w] = x;
    __syncthreads();
    int wbase = 0;
    for (int k = 0; k < w; ++k) wbase += wsum[k];
    int base = base_sh;
    if (i < n){ int e = base + wbase + x - v; offs[i] = e; cur[i] = e; }
    __syncthreads();
    if (t == 1023){
      int tot = 0;
      for (int k = 0; k < 16; ++k) tot += wsum[k];
      base_sh = base + tot;
    }
    __syncthreads();
  }
  if (threadIdx.x == 0) offs[n] = base_sh;
}

__global__ void k_csr_fill(const int* __restrict__ src, const int* __restrict__ dst,
                           int* __restrict__ cur, int* __restrict__ csr_src, int E){
  int k = blockIdx.x * 256 + threadIdx.x;
  if (k >= E) return;
  int pos = atomicAdd(cur + dst[k], 1);
  csr_src[pos] = src[k];
}

// ============ fused GATv2 aggregation: one wave per dst node ============
// out[d, oo:oo+64] = sum_e exp(e)*fs[src_e] / sum_e exp(e) + bias (+ res)
// (no max-subtraction: |e| = |attn.lrelu(...)| << 80 at these scales, so
//  exp(e)/sum exp(e) == reference exp(e-m)/sum exp(e-m) exactly in math)
__global__ void k_gat(const int* __restrict__ offs, const int* __restrict__ csr_src,
                      const float* __restrict__ fs, const float* __restrict__ fd,
                      const float* __restrict__ attn, const float* __restrict__ bias,
                      float* __restrict__ out, int os, int oo,
                      const float* __restrict__ res, int rs, int ro, int n){
  int d = blockIdx.x * 4 + (threadIdx.x >> 6);
  if (d >= n) return;
  int j = threadIdx.x & 63;
  float fdv = fd[(size_t)d * 64 + j];
  float aj  = attn[j];
  float acc = 0.f, den = 0.f;
  int e0 = offs[d], e1 = offs[d + 1];
  for (int idx = e0; idx < e1; ++idx){
    int s = csr_src[idx];
    float fsv = fs[(size_t)s * 64 + j];
    float v = fsv + fdv;
    v = v > 0.f ? v : 0.2f * v;
    float e = wave_sum_all(v * aj);
    float ex = __expf(e);
    acc += ex * fsv;
    den += ex;
  }
  float o = (den > 0.f) ? acc / den : 0.f;   // empty segment -> bias only
  o += bias[j];
  if (res) o += res[(size_t)d * rs + ro + j];
  out[(size_t)d * os + oo + j] = o;
}

// ---- collapse attention-gate MLP: v = W1@W2 (per l,i), c = b1@W2 + b2 ----
__global__ void k_attvec(const float* __restrict__ W1, const float* __restrict__ b1,
                         const float* __restrict__ W2, const float* __restrict__ b2,
                         float* __restrict__ vvec, float* __restrict__ cs){
  int t = threadIdx.x;           // 512 threads: (l*2+i) in [0,4), r in [0,128)
  int li = t >> 7, r = t & 127;
  float acc = 0.f;
  for (int c = 0; c < 128; ++c)
    acc += W1[(size_t)(li * 128 + r) * 128 + c] * W2[li * 128 + c];
  vvec[li * 128 + r] = acc;
  if (r == 0){
    float cacc = b2[li];
    for (int c = 0; c < 128; ++c)
      cacc += b1[li * 128 + c] * W2[li * 128 + c];
    cs[li] = cacc;
  }
}

// ---- gate z-scores + per-block partial sums for BatchNorm ----
__global__ void k_gate_z(const float* __restrict__ hu_all, int l,
                         const float* __restrict__ p, const float* __restrict__ q,
                         const float* __restrict__ vvec, const float* __restrict__ cs,
                         float* __restrict__ z1, float* __restrict__ z2,
                         float* __restrict__ bsums, int n){
  __shared__ float part[4][4];
  int w = threadIdx.x >> 6, j = threadIdx.x & 63;
  int nidx = blockIdx.x * 4 + w;
  float lz1 = 0.f, lz2 = 0.f;
  if (nidx < n){
    const float* v1 = vvec + l * 256;
    const float* v2 = vvec + l * 256 + 128;
    float h  = hu_all[(size_t)nidx * 192 + l * 64 + j];
    float pv = p[(size_t)nidx * 64 + j];
    float qv = q[(size_t)nidx * 64 + j];
    float t1 = wave_sum(h * v1[j] + pv * v1[64 + j]);
    float t2 = wave_sum(h * v2[j] + qv * v2[64 + j]);
    if (j == 0){
      lz1 = t1 + cs[l * 2 + 0];
      lz2 = t2 + cs[l * 2 + 1];
      z1[nidx] = lz1;
      z2[nidx] = lz2;
    }
  }
  if (j == 0){
    part[w][0] = lz1; part[w][1] = lz1 * lz1;
    part[w][2] = lz2; part[w][3] = lz2 * lz2;
  }
  __syncthreads();
  if (threadIdx.x < 4)
    bsums[(size_t)blockIdx.x * 4 + threadIdx.x] =
        part[0][threadIdx.x] + part[1][threadIdx.x] +
        part[2][threadIdx.x] + part[3][threadIdx.x];
}

// ---- deterministic reduce of per-block partials -> sums[4] (f64) ----
__global__ void k_bn_reduce(const float* __restrict__ bsums, int nb,
                            double* __restrict__ sums){
  __shared__ double sh[256];
  int c = threadIdx.x & 3, chunk = threadIdx.x >> 2;
  double acc = 0.0;
  for (int i = chunk; i < nb; i += 64) acc += (double)bsums[(size_t)i * 4 + c];
  sh[threadIdx.x] = acc;
  __syncthreads();
  for (int s = 128; s >= 4; s >>= 1){
    if (threadIdx.x < s) sh[threadIdx.x] += sh[threadIdx.x + s];
    __syncthreads();
  }
  if (threadIdx.x < 4) sums[threadIdx.x] = sh[threadIdx.x];
}

// ---- BN + lrelu(0.01) + softmax gate + residual combine -> hu_all block l+1 ----
__global__ void k_gate_combine(float* __restrict__ hu_all, int l,
                               const float* __restrict__ p, const float* __restrict__ q,
                               const float* __restrict__ z1, const float* __restrict__ z2,
                               const double* __restrict__ sums, int n){
  int idx = blockIdx.x * 256 + threadIdx.x;
  if (idx >= n * 64) return;
  int r = idx >> 6, j = idx & 63;
  double invn = 1.0 / (double)n;
  double mu1 = sums[0] * invn, mu2 = sums[2] * invn;
  float var1 = (float)(sums[1] * invn - mu1 * mu1);
  float var2 = (float)(sums[3] * invn - mu2 * mu2);
  float rs1 = rsqrtf(var1 + 1e-5f), rs2 = rsqrtf(var2 + 1e-5f);
  float a1 = (z1[r] - (float)mu1) * rs1;
  float a2 = (z2[r] - (float)mu2) * rs2;
  a1 = a1 > 0.f ? a1 : 0.01f * a1;
  a2 = a2 > 0.f ? a2 : 0.01f * a2;
  float mx = fmaxf(a1, a2);
  float e1 = __expf(a1 - mx), e2 = __expf(a2 - mx);
  float inv = 1.f / (e1 + e2);
  float out = (e1 * inv) * p[idx] + (e2 * inv) * q[idx]
            + hu_all[(size_t)r * 192 + l * 64 + j];
  hu_all[(size_t)r * 192 + (l + 1) * 64 + j] = out;
}

// ---- final scoring: dot(hu_all[u], hi_all[i]) over 192 dims ----
__global__ void k_score(const int* __restrict__ pu, const int* __restrict__ pi,
                        const int* __restrict__ nu, const int* __restrict__ ni,
                        const float* __restrict__ hu_all, const float* __restrict__ hi_all,
                        float* __restrict__ out, int EP){
  int k = blockIdx.x * 4 + (threadIdx.x >> 6);
  if (k >= 2 * EP) return;
  int j = threadIdx.x & 63;
  int u, i;
  if (k < EP){ u = pu[k]; i = pi[k]; } else { u = nu[k - EP]; i = ni[k - EP]; }
  const float* hu = hu_all + (size_t)u * 192;
  const float* hi = hi_all + (size_t)i * 192;
  float acc = hu[j] * hi[j] + hu[j + 64] * hi[j + 64] + hu[j + 128] * hi[j + 128];
  acc = wave_sum(acc);
  if (j == 0) out[k] = acc;
}

extern "C" void kernel_launch(void* const* d_in, const int* in_sizes, int n_in,
                              void* d_out, int out_size, void* d_ws, size_t ws_size,
                              hipStream_t stream) {
  const int*   rate_src  = (const int*)  d_in[0];
  const int*   rate_dst  = (const int*)  d_in[1];
  const int*   trust_src = (const int*)  d_in[2];
  const int*   trust_dst = (const int*)  d_in[3];
  const int*   pos_u     = (const int*)  d_in[4];
  const int*   pos_i     = (const int*)  d_in[5];
  const int*   neg_u     = (const int*)  d_in[6];
  const int*   neg_i     = (const int*)  d_in[7];
  const float* eu        = (const float*)d_in[8];
  const float* ei        = (const float*)d_in[9];
  const float* rate_W    = (const float*)d_in[10];
  const float* rate_b    = (const float*)d_in[11];
  const float* rate_attn = (const float*)d_in[12];
  const float* rate_bias = (const float*)d_in[13];
  const float* rb_W      = (const float*)d_in[14];
  const float* rb_b      = (const float*)d_in[15];
  const float* rb_attn   = (const float*)d_in[16];
  const float* rb_bias   = (const float*)d_in[17];
  const float* tr_W      = (const float*)d_in[18];
  const float* tr_b      = (const float*)d_in[19];
  const float* tr_attn   = (const float*)d_in[20];
  const float* tr_bias   = (const float*)d_in[21];
  const float* attW1     = (const float*)d_in[22];
  const float* attb1     = (const float*)d_in[23];
  const float* attW2     = (const float*)d_in[24];
  const float* attb2     = (const float*)d_in[25];

  const int ER = in_sizes[0];
  const int ET = in_sizes[2];
  const int EP = in_sizes[4];
  const int NU = in_sizes[8] / 64;
  const int NI = in_sizes[9] / 64;

  // ---- workspace layout: f32 region then int region (~231 MiB) ----
  float* ws = (float*)d_ws;
  float*  hu_all = ws;                                   // NU*192
  float*  hi_all = hu_all + (size_t)NU * 192;            // NI*192
  float*  p      = hi_all + (size_t)NI * 192;            // NU*64
  float*  q      = p + (size_t)NU * 64;                  // NU*64
  float*  fs     = q + (size_t)NU * 64;                  // NU*64
  float*  fd     = fs + (size_t)NU * 64;                 // NU*64
  float*  z1     = fd + (size_t)NU * 64;                 // NU
  float*  z2     = z1 + NU;                              // NU
  float*  bsums  = z2 + NU;                              // cdiv(NU,4)*4
  float*  vvec   = bsums + (size_t)(((NU + 3) / 4) * 4); // 512
  float*  cs     = vvec + 512;                           // 4
  double* sums   = (double*)(((uintptr_t)(cs + 4) + 15) & ~(uintptr_t)15); // 4
  int*    iw     = (int*)(sums + 4);
  int*    offsA  = iw;                // NI+1   rate grouped by item
  int*    offsB  = offsA + (NI + 1);  // NU+1   rate grouped by user
  int*    offsC  = offsB + (NU + 1);  // NU+1   trust grouped by dst user
  int*    csrA   = offsC + (NU + 1);  // ER     (stores user src)
  int*    csrB   = csrA + ER;         // ER     (stores item src)
  int*    csrC   = csrB + ER;         // ET     (stores user src)
  int*    cnt    = csrC + ET;         // NU     (shared cnt/cursor)

  auto cdiv = [](int a, int b){ return (a + b - 1) / b; };
  const int nbz = cdiv(NU, 4);

  // ---- one-time per call: init state + gate MLP collapse + CSR builds ----
  k_copy_in<<<cdiv(NU * 64, 256), 256, 0, stream>>>(eu, hu_all, NU, 192);
  k_copy_in<<<cdiv(NI * 64, 256), 256, 0, stream>>>(ei, hi_all, NI, 192);
  k_attvec<<<1, 512, 0, stream>>>(attW1, attb1, attW2, attb2, vvec, cs);

  // CSR A: rate edges by item (dst=rate_dst), store user
  hipMemsetAsync(cnt, 0, (size_t)NI * 4, stream);
  k_hist<<<cdiv(ER, 256), 256, 0, stream>>>(rate_dst, cnt, ER);
  k_scan<<<1, 1024, 0, stream>>>(cnt, NI, offsA, cnt);
  k_csr_fill<<<cdiv(ER, 256), 256, 0, stream>>>(rate_src, rate_dst, cnt, csrA, ER);
  // CSR B: rate edges by user (dst=rate_src), store item
  hipMemsetAsync(cnt, 0, (size_t)NU * 4, stream);
  k_hist<<<cdiv(ER, 256), 256, 0, stream>>>(rate_src, cnt, ER);
  k_scan<<<1, 1024, 0, stream>>>(cnt, NU, offsB, cnt);
  k_csr_fill<<<cdiv(ER, 256), 256, 0, stream>>>(rate_dst, rate_src, cnt, csrB, ER);
  // CSR C: trust edges by dst user, store src user
  hipMemsetAsync(cnt, 0, (size_t)NU * 4, stream);
  k_hist<<<cdiv(ET, 256), 256, 0, stream>>>(trust_dst, cnt, ET);
  k_scan<<<1, 1024, 0, stream>>>(cnt, NU, offsC, cnt);
  k_csr_fill<<<cdiv(ET, 256), 256, 0, stream>>>(trust_src, trust_dst, cnt, csrC, ET);

  for (int l = 0; l < 2; ++l){
    // ---------- rate GAT: users -> items, into hi_all block l+1 (+bias+residual) ----------
    k_linear<<<cdiv(NU, 16), 256, 0, stream>>>(hu_all, 192, l * 64,
        rate_W + (size_t)(l * 2 + 0) * 4096, rate_b + (l * 2 + 0) * 64, fs, NU);
    k_linear<<<cdiv(NI, 16), 256, 0, stream>>>(hi_all, 192, l * 64,
        rate_W + (size_t)(l * 2 + 1) * 4096, rate_b + (l * 2 + 1) * 64, fd, NI);
    k_gat<<<cdiv(NI, 4), 256, 0, stream>>>(offsA, csrA, fs, fd,
        rate_attn + l * 64, rate_bias + l * 64,
        hi_all, 192, (l + 1) * 64, hi_all, 192, l * 64, NI);

    // ---------- rated-by GAT: items -> users, result q ----------
    k_linear<<<cdiv(NI, 16), 256, 0, stream>>>(hi_all, 192, l * 64,
        rb_W + (size_t)(l * 2 + 0) * 4096, rb_b + (l * 2 + 0) * 64, fs, NI);
    k_linear<<<cdiv(NU, 16), 256, 0, stream>>>(hu_all, 192, l * 64,
        rb_W + (size_t)(l * 2 + 1) * 4096, rb_b + (l * 2 + 1) * 64, fd, NU);
    k_gat<<<cdiv(NU, 4), 256, 0, stream>>>(offsB, csrB, fs, fd,
        rb_attn + l * 64, rb_bias + l * 64,
        q, 64, 0, (const float*)nullptr, 0, 0, NU);

    // ---------- trust GAT: users -> users, result p ----------
    k_linear<<<cdiv(NU, 16), 256, 0, stream>>>(hu_all, 192, l * 64,
        tr_W + (size_t)(l * 2 + 0) * 4096, tr_b + (l * 2 + 0) * 64, fs, NU);
    k_linear<<<cdiv(NU, 16), 256, 0, stream>>>(hu_all, 192, l * 64,
        tr_W + (size_t)(l * 2 + 1) * 4096, tr_b + (l * 2 + 1) * 64, fd, NU);
    k_gat<<<cdiv(NU, 4), 256, 0, stream>>>(offsC, csrC, fs, fd,
        tr_attn + l * 64, tr_bias + l * 64,
        p, 64, 0, (const float*)nullptr, 0, 0, NU);

    // ---------- attention gate + combine -> hu_all block l+1 ----------
    k_gate_z<<<nbz, 256, 0, stream>>>(hu_all, l, p, q, vvec, cs, z1, z2, bsums, NU);
    k_bn_reduce<<<1, 256, 0, stream>>>(bsums, nbz, sums);
    k_gate_combine<<<cdiv(NU * 64, 256), 256, 0, stream>>>(hu_all, l, p, q, z1, z2, sums, NU);
  }

  // ---------- final scoring ----------
  k_score<<<cdiv(2 * EP, 4), 256, 0, stream>>>(pos_u, pos_i, neg_u, neg_i,
      hu_all, hi_all, (float*)d_out, EP);
}

// Round 5
// 1703.956 us; speedup vs baseline: 1.9625x; 1.3324x over previous
//
#include <hip/hip_runtime.h>
#include <hip/hip_bf16.h>
#include <cstdint>

// butterfly: all lanes end with the full 64-lane sum
__device__ __forceinline__ float wave_sum_all(float v){
#pragma unroll
  for (int o = 32; o > 0; o >>= 1) v += __shfl_xor(v, o, 64);
  return v;
}
__device__ __forceinline__ float wave_sum(float v){
#pragma unroll
  for (int o = 32; o > 0; o >>= 1) v += __shfl_down(v, o, 64);
  return v;  // lane 0 holds the sum
}

// ---- copy f32 [n,64] -> f32 strided [n, stride] ----
__global__ void k_copy_in(const float* __restrict__ src, float* __restrict__ dst,
                          int n, int stride){
  int idx = blockIdx.x * 256 + threadIdx.x;
  if (idx >= n * 64) return;
  int r = idx >> 6, j = idx & 63;
  dst[(size_t)r * stride + j] = src[idx];
}

// ---- fs[n,64] = x[n, xo:xo+64] @ W(64x64) + b ----
__global__ void k_linear(const float* __restrict__ x, int xs, int xo,
                         const float* __restrict__ W, const float* __restrict__ b,
                         float* __restrict__ out, int n){
  __shared__ float Wf[64 * 64];
  __shared__ float xsh[16][64];
  int t = threadIdx.x;
  for (int i = t; i < 4096; i += 256) Wf[i] = W[i];
  int base = blockIdx.x * 16;
  for (int i = t; i < 16 * 64; i += 256){
    int r = i >> 6, j = i & 63;
    int nn = base + r;
    xsh[r][j] = (nn < n) ? x[(size_t)nn * xs + xo + j] : 0.f;
  }
  __syncthreads();
  int j = t & 63, w = t >> 6;
  float bj = b[j];
  for (int r = w; r < 16; r += 4){
    int nn = base + r;
    if (nn >= n) continue;
    float acc = bj;
#pragma unroll
    for (int k = 0; k < 64; ++k)
      acc += xsh[r][k] * Wf[k * 64 + j];
    out[(size_t)nn * 64 + j] = acc;
  }
}

// ================= CSR build (per call; ws is re-poisoned) =================
__global__ void k_hist(const int* __restrict__ dst, int* __restrict__ cnt, int E){
  int k = blockIdx.x * 256 + threadIdx.x;
  if (k < E) atomicAdd(cnt + dst[k], 1);
}

// multi-block scan: each block allocates a contiguous range for its 1024-chunk
// via atomicAdd on gbase. Offsets are disjoint but NOT globally monotone ->
// consumers use cnt[] for segment ends (each segment itself is contiguous).
__global__ void k_scan_mb(const int* __restrict__ cnt, int n,
                          int* __restrict__ offs, int* __restrict__ cur,
                          int* __restrict__ gbase){
  __shared__ int wsum[16];
  __shared__ int base_sh;
  int t = threadIdx.x, lane = t & 63, w = t >> 6;
  int i = blockIdx.x * 1024 + t;
  int v = (i < n) ? cnt[i] : 0;
  int x = v;                       // inclusive scan within wave
#pragma unroll
  for (int o = 1; o < 64; o <<= 1){
    int y = __shfl_up(x, o, 64);
    if (lane >= o) x += y;
  }
  if (lane == 63) wsum[w] = x;
  __syncthreads();
  if (t == 0){
    int tot = 0;
    for (int k = 0; k < 16; ++k){ int c = wsum[k]; wsum[k] = tot; tot += c; }
    base_sh = atomicAdd(gbase, tot);
  }
  __syncthreads();
  if (i < n){
    int e = base_sh + wsum[w] + x - v;
    offs[i] = e; cur[i] = e;
  }
}

__global__ void k_csr_fill(const int* __restrict__ src, const int* __restrict__ dst,
                           int* __restrict__ cur, int* __restrict__ csr_src, int E){
  int k = blockIdx.x * 256 + threadIdx.x;
  if (k >= E) return;
  int pos = atomicAdd(cur + dst[k], 1);
  csr_src[pos] = src[k];
}

// ============ fused GATv2 aggregation: one wave per dst node ============
// 4-way unrolled: 4 src rows in flight per iteration (MLP to hide L2 latency;
// VGPR_Count=12 in the 1-edge version showed the compiler doesn't pipeline).
__global__ void k_gat(const int* __restrict__ offs, const int* __restrict__ cnt,
                      const int* __restrict__ csr_src,
                      const float* __restrict__ fs, const float* __restrict__ fd,
                      const float* __restrict__ attn, const float* __restrict__ bias,
                      float* __restrict__ out, int os, int oo,
                      const float* __restrict__ res, int rs, int ro, int n){
  int d = blockIdx.x * 4 + (threadIdx.x >> 6);
  if (d >= n) return;
  int j = threadIdx.x & 63;
  float fdv = fd[(size_t)d * 64 + j];
  float aj  = attn[j];
  float acc = 0.f, den = 0.f;
  int idx = offs[d], end = idx + cnt[d];
  for (; idx + 4 <= end; idx += 4){
    int s0 = csr_src[idx + 0], s1 = csr_src[idx + 1],
        s2 = csr_src[idx + 2], s3 = csr_src[idx + 3];
    float f0 = fs[(size_t)s0 * 64 + j], f1 = fs[(size_t)s1 * 64 + j],
          f2 = fs[(size_t)s2 * 64 + j], f3 = fs[(size_t)s3 * 64 + j];
    float v0 = f0 + fdv; v0 = (v0 > 0.f ? v0 : 0.2f * v0) * aj;
    float v1 = f1 + fdv; v1 = (v1 > 0.f ? v1 : 0.2f * v1) * aj;
    float v2 = f2 + fdv; v2 = (v2 > 0.f ? v2 : 0.2f * v2) * aj;
    float v3 = f3 + fdv; v3 = (v3 > 0.f ? v3 : 0.2f * v3) * aj;
#pragma unroll
    for (int o = 32; o > 0; o >>= 1){
      v0 += __shfl_xor(v0, o, 64); v1 += __shfl_xor(v1, o, 64);
      v2 += __shfl_xor(v2, o, 64); v3 += __shfl_xor(v3, o, 64);
    }
    float ex0 = __expf(v0), ex1 = __expf(v1), ex2 = __expf(v2), ex3 = __expf(v3);
    acc += ex0 * f0; acc += ex1 * f1; acc += ex2 * f2; acc += ex3 * f3;
    den += (ex0 + ex1) + (ex2 + ex3);
  }
  for (; idx < end; ++idx){
    int s = csr_src[idx];
    float fsv = fs[(size_t)s * 64 + j];
    float v = fsv + fdv;
    v = (v > 0.f ? v : 0.2f * v) * aj;
    float e = wave_sum_all(v);
    float ex = __expf(e);
    acc += ex * fsv;
    den += ex;
  }
  float o = (den > 0.f) ? acc / den : 0.f;   // empty segment -> bias only
  o += bias[j];
  if (res) o += res[(size_t)d * rs + ro + j];
  out[(size_t)d * os + oo + j] = o;
}

// ---- collapse attention-gate MLP: v = W1@W2 (per l,i), c = b1@W2 + b2 ----
__global__ void k_attvec(const float* __restrict__ W1, const float* __restrict__ b1,
                         const float* __restrict__ W2, const float* __restrict__ b2,
                         float* __restrict__ vvec, float* __restrict__ cs){
  int t = threadIdx.x;           // 512 threads: (l*2+i) in [0,4), r in [0,128)
  int li = t >> 7, r = t & 127;
  float acc = 0.f;
  for (int c = 0; c < 128; ++c)
    acc += W1[(size_t)(li * 128 + r) * 128 + c] * W2[li * 128 + c];
  vvec[li * 128 + r] = acc;
  if (r == 0){
    float cacc = b2[li];
    for (int c = 0; c < 128; ++c)
      cacc += b1[li * 128 + c] * W2[li * 128 + c];
    cs[li] = cacc;
  }
}

// ---- gate z-scores + per-block partial sums for BatchNorm ----
__global__ void k_gate_z(const float* __restrict__ hu_all, int l,
                         const float* __restrict__ p, const float* __restrict__ q,
                         const float* __restrict__ vvec, const float* __restrict__ cs,
                         float* __restrict__ z1, float* __restrict__ z2,
                         float* __restrict__ bsums, int n){
  __shared__ float part[4][4];
  int w = threadIdx.x >> 6, j = threadIdx.x & 63;
  int nidx = blockIdx.x * 4 + w;
  float lz1 = 0.f, lz2 = 0.f;
  if (nidx < n){
    const float* v1 = vvec + l * 256;
    const float* v2 = vvec + l * 256 + 128;
    float h  = hu_all[(size_t)nidx * 192 + l * 64 + j];
    float pv = p[(size_t)nidx * 64 + j];
    float qv = q[(size_t)nidx * 64 + j];
    float t1 = wave_sum(h * v1[j] + pv * v1[64 + j]);
    float t2 = wave_sum(h * v2[j] + qv * v2[64 + j]);
    if (j == 0){
      lz1 = t1 + cs[l * 2 + 0];
      lz2 = t2 + cs[l * 2 + 1];
      z1[nidx] = lz1;
      z2[nidx] = lz2;
    }
  }
  if (j == 0){
    part[w][0] = lz1; part[w][1] = lz1 * lz1;
    part[w][2] = lz2; part[w][3] = lz2 * lz2;
  }
  __syncthreads();
  if (threadIdx.x < 4)
    bsums[(size_t)blockIdx.x * 4 + threadIdx.x] =
        part[0][threadIdx.x] + part[1][threadIdx.x] +
        part[2][threadIdx.x] + part[3][threadIdx.x];
}

// ---- deterministic reduce of per-block partials -> sums[4] (f64) ----
__global__ void k_bn_reduce(const float* __restrict__ bsums, int nb,
                            double* __restrict__ sums){
  __shared__ double sh[256];
  int c = threadIdx.x & 3, chunk = threadIdx.x >> 2;
  double acc = 0.0;
  for (int i = chunk; i < nb; i += 64) acc += (double)bsums[(size_t)i * 4 + c];
  sh[threadIdx.x] = acc;
  __syncthreads();
  for (int s = 128; s >= 4; s >>= 1){
    if (threadIdx.x < s) sh[threadIdx.x] += sh[threadIdx.x + s];
    __syncthreads();
  }
  if (threadIdx.x < 4) sums[threadIdx.x] = sh[threadIdx.x];
}

// ---- BN + lrelu(0.01) + softmax gate + residual combine -> hu_all block l+1 ----
__global__ void k_gate_combine(float* __restrict__ hu_all, int l,
                               const float* __restrict__ p, const float* __restrict__ q,
                               const float* __restrict__ z1, const float* __restrict__ z2,
                               const double* __restrict__ sums, int n){
  int idx = blockIdx.x * 256 + threadIdx.x;
  if (idx >= n * 64) return;
  int r = idx >> 6, j = idx & 63;
  double invn = 1.0 / (double)n;
  double mu1 = sums[0] * invn, mu2 = sums[2] * invn;
  float var1 = (float)(sums[1] * invn - mu1 * mu1);
  float var2 = (float)(sums[3] * invn - mu2 * mu2);
  float rs1 = rsqrtf(var1 + 1e-5f), rs2 = rsqrtf(var2 + 1e-5f);
  float a1 = (z1[r] - (float)mu1) * rs1;
  float a2 = (z2[r] - (float)mu2) * rs2;
  a1 = a1 > 0.f ? a1 : 0.01f * a1;
  a2 = a2 > 0.f ? a2 : 0.01f * a2;
  float mx = fmaxf(a1, a2);
  float e1 = __expf(a1 - mx), e2 = __expf(a2 - mx);
  float inv = 1.f / (e1 + e2);
  float out = (e1 * inv) * p[idx] + (e2 * inv) * q[idx]
            + hu_all[(size_t)r * 192 + l * 64 + j];
  hu_all[(size_t)r * 192 + (l + 1) * 64 + j] = out;
}

// ---- final scoring: dot(hu_all[u], hi_all[i]) over 192 dims ----
__global__ void k_score(const int* __restrict__ pu, const int* __restrict__ pi,
                        const int* __restrict__ nu, const int* __restrict__ ni,
                        const float* __restrict__ hu_all, const float* __restrict__ hi_all,
                        float* __restrict__ out, int EP){
  int k = blockIdx.x * 4 + (threadIdx.x >> 6);
  if (k >= 2 * EP) return;
  int j = threadIdx.x & 63;
  int u, i;
  if (k < EP){ u = pu[k]; i = pi[k]; } else { u = nu[k - EP]; i = ni[k - EP]; }
  const float* hu = hu_all + (size_t)u * 192;
  const float* hi = hi_all + (size_t)i * 192;
  float acc = hu[j] * hi[j] + hu[j + 64] * hi[j + 64] + hu[j + 128] * hi[j + 128];
  acc = wave_sum(acc);
  if (j == 0) out[k] = acc;
}

extern "C" void kernel_launch(void* const* d_in, const int* in_sizes, int n_in,
                              void* d_out, int out_size, void* d_ws, size_t ws_size,
                              hipStream_t stream) {
  const int*   rate_src  = (const int*)  d_in[0];
  const int*   rate_dst  = (const int*)  d_in[1];
  const int*   trust_src = (const int*)  d_in[2];
  const int*   trust_dst = (const int*)  d_in[3];
  const int*   pos_u     = (const int*)  d_in[4];
  const int*   pos_i     = (const int*)  d_in[5];
  const int*   neg_u     = (const int*)  d_in[6];
  const int*   neg_i     = (const int*)  d_in[7];
  const float* eu        = (const float*)d_in[8];
  const float* ei        = (const float*)d_in[9];
  const float* rate_W    = (const float*)d_in[10];
  const float* rate_b    = (const float*)d_in[11];
  const float* rate_attn = (const float*)d_in[12];
  const float* rate_bias = (const float*)d_in[13];
  const float* rb_W      = (const float*)d_in[14];
  const float* rb_b      = (const float*)d_in[15];
  const float* rb_attn   = (const float*)d_in[16];
  const float* rb_bias   = (const float*)d_in[17];
  const float* tr_W      = (const float*)d_in[18];
  const float* tr_b      = (const float*)d_in[19];
  const float* tr_attn   = (const float*)d_in[20];
  const float* tr_bias   = (const float*)d_in[21];
  const float* attW1     = (const float*)d_in[22];
  const float* attb1     = (const float*)d_in[23];
  const float* attW2     = (const float*)d_in[24];
  const float* attb2     = (const float*)d_in[25];

  const int ER = in_sizes[0];
  const int ET = in_sizes[2];
  const int EP = in_sizes[4];
  const int NU = in_sizes[8] / 64;
  const int NI = in_sizes[9] / 64;

  // ---- workspace layout: f32 region then int region ----
  float* ws = (float*)d_ws;
  float*  hu_all = ws;                                   // NU*192
  float*  hi_all = hu_all + (size_t)NU * 192;            // NI*192
  float*  p      = hi_all + (size_t)NI * 192;            // NU*64
  float*  q      = p + (size_t)NU * 64;                  // NU*64
  float*  fs     = q + (size_t)NU * 64;                  // NU*64
  float*  fd     = fs + (size_t)NU * 64;                 // NU*64
  float*  z1     = fd + (size_t)NU * 64;                 // NU
  float*  z2     = z1 + NU;                              // NU
  float*  bsums  = z2 + NU;                              // cdiv(NU,4)*4
  float*  vvec   = bsums + (size_t)(((NU + 3) / 4) * 4); // 512
  float*  cs     = vvec + 512;                           // 4
  double* sums   = (double*)(((uintptr_t)(cs + 4) + 15) & ~(uintptr_t)15); // 4
  int*    iw     = (int*)(sums + 4);
  // counts (contiguous: one memset) then bases then offs/cur then csr arrays
  int*    cntA   = iw;                 // NI
  int*    cntB   = cntA + NI;          // NU
  int*    cntC   = cntB + NU;          // NU
  int*    gbase  = cntC + NU;          // 4 (3 used)
  int*    offsA  = gbase + 4;          // NI
  int*    curA   = offsA + NI;         // NI
  int*    offsB  = curA + NI;          // NU
  int*    curB   = offsB + NU;         // NU
  int*    offsC  = curB + NU;          // NU
  int*    curC   = offsC + NU;         // NU
  int*    csrA   = curC + NU;          // ER (user srcs, grouped by item)
  int*    csrB   = csrA + ER;          // ER (item srcs, grouped by user)
  int*    csrC   = csrB + ER;          // ET (user srcs, grouped by dst user)

  auto cdiv = [](int a, int b){ return (a + b - 1) / b; };
  const int nbz = cdiv(NU, 4);

  // ---- one-time per call: init state + gate MLP collapse + CSR builds ----
  k_copy_in<<<cdiv(NU * 64, 256), 256, 0, stream>>>(eu, hu_all, NU, 192);
  k_copy_in<<<cdiv(NI * 64, 256), 256, 0, stream>>>(ei, hi_all, NI, 192);
  k_attvec<<<1, 512, 0, stream>>>(attW1, attb1, attW2, attb2, vvec, cs);

  // zero all counts + base cursors in one shot (contiguous)
  hipMemsetAsync(cntA, 0, (size_t)(NI + 2 * NU + 4) * 4, stream);
  k_hist<<<cdiv(ER, 256), 256, 0, stream>>>(rate_dst, cntA, ER);
  k_hist<<<cdiv(ER, 256), 256, 0, stream>>>(rate_src, cntB, ER);
  k_hist<<<cdiv(ET, 256), 256, 0, stream>>>(trust_dst, cntC, ET);
  k_scan_mb<<<cdiv(NI, 1024), 1024, 0, stream>>>(cntA, NI, offsA, curA, gbase + 0);
  k_scan_mb<<<cdiv(NU, 1024), 1024, 0, stream>>>(cntB, NU, offsB, curB, gbase + 1);
  k_scan_mb<<<cdiv(NU, 1024), 1024, 0, stream>>>(cntC, NU, offsC, curC, gbase + 2);
  k_csr_fill<<<cdiv(ER, 256), 256, 0, stream>>>(rate_src, rate_dst, curA, csrA, ER);
  k_csr_fill<<<cdiv(ER, 256), 256, 0, stream>>>(rate_dst, rate_src, curB, csrB, ER);
  k_csr_fill<<<cdiv(ET, 256), 256, 0, stream>>>(trust_src, trust_dst, curC, csrC, ET);

  for (int l = 0; l < 2; ++l){
    // ---------- rate GAT: users -> items, into hi_all block l+1 (+bias+residual) ----------
    k_linear<<<cdiv(NU, 16), 256, 0, stream>>>(hu_all, 192, l * 64,
        rate_W + (size_t)(l * 2 + 0) * 4096, rate_b + (l * 2 + 0) * 64, fs, NU);
    k_linear<<<cdiv(NI, 16), 256, 0, stream>>>(hi_all, 192, l * 64,
        rate_W + (size_t)(l * 2 + 1) * 4096, rate_b + (l * 2 + 1) * 64, fd, NI);
    k_gat<<<cdiv(NI, 4), 256, 0, stream>>>(offsA, cntA, csrA, fs, fd,
        rate_attn + l * 64, rate_bias + l * 64,
        hi_all, 192, (l + 1) * 64, hi_all, 192, l * 64, NI);

    // ---------- rated-by GAT: items -> users, result q ----------
    k_linear<<<cdiv(NI, 16), 256, 0, stream>>>(hi_all, 192, l * 64,
        rb_W + (size_t)(l * 2 + 0) * 4096, rb_b + (l * 2 + 0) * 64, fs, NI);
    k_linear<<<cdiv(NU, 16), 256, 0, stream>>>(hu_all, 192, l * 64,
        rb_W + (size_t)(l * 2 + 1) * 4096, rb_b + (l * 2 + 1) * 64, fd, NU);
    k_gat<<<cdiv(NU, 4), 256, 0, stream>>>(offsB, cntB, csrB, fs, fd,
        rb_attn + l * 64, rb_bias + l * 64,
        q, 64, 0, (const float*)nullptr, 0, 0, NU);

    // ---------- trust GAT: users -> users, result p ----------
    k_linear<<<cdiv(NU, 16), 256, 0, stream>>>(hu_all, 192, l * 64,
        tr_W + (size_t)(l * 2 + 0) * 4096, tr_b + (l * 2 + 0) * 64, fs, NU);
    k_linear<<<cdiv(NU, 16), 256, 0, stream>>>(hu_all, 192, l * 64,
        tr_W + (size_t)(l * 2 + 1) * 4096, tr_b + (l * 2 + 1) * 64, fd, NU);
    k_gat<<<cdiv(NU, 4), 256, 0, stream>>>(offsC, cntC, csrC, fs, fd,
        tr_attn + l * 64, tr_bias + l * 64,
        p, 64, 0, (const float*)nullptr, 0, 0, NU);

    // ---------- attention gate + combine -> hu_all block l+1 ----------
    k_gate_z<<<nbz, 256, 0, stream>>>(hu_all, l, p, q, vvec, cs, z1, z2, bsums, NU);
    k_bn_reduce<<<1, 256, 0, stream>>>(bsums, nbz, sums);
    k_gate_combine<<<cdiv(NU * 64, 256), 256, 0, stream>>>(hu_all, l, p, q, z1, z2, sums, NU);
  }

  // ---------- final scoring ----------
  k_score<<<cdiv(2 * EP, 4), 256, 0, stream>>>(pos_u, pos_i, neg_u, neg_i,
      hu_all, hi_all, (float*)d_out, EP);
}

// Round 6
// 1524.121 us; speedup vs baseline: 2.1941x; 1.1180x over previous
//
#include <hip/hip_runtime.h>
#include <hip/hip_bf16.h>
#include <cstdint>

// butterfly: all lanes end with the full 64-lane sum
__device__ __forceinline__ float wave_sum_all(float v){
#pragma unroll
  for (int o = 32; o > 0; o >>= 1) v += __shfl_xor(v, o, 64);
  return v;
}
__device__ __forceinline__ float wave_sum(float v){
#pragma unroll
  for (int o = 32; o > 0; o >>= 1) v += __shfl_down(v, o, 64);
  return v;  // lane 0 holds the sum
}

// ---- copy f32 [n,64] -> f32 strided [n, stride] ----
__global__ void k_copy_in(const float* __restrict__ src, float* __restrict__ dst,
                          int n, int stride){
  int idx = blockIdx.x * 256 + threadIdx.x;
  if (idx >= n * 64) return;
  int r = idx >> 6, j = idx & 63;
  dst[(size_t)r * stride + j] = src[idx];
}

// ---- fs[n,64] = x[n, xo:xo+64] @ W(64x64) + b ----
__global__ void k_linear(const float* __restrict__ x, int xs, int xo,
                         const float* __restrict__ W, const float* __restrict__ b,
                         float* __restrict__ out, int n){
  __shared__ float Wf[64 * 64];
  __shared__ float xsh[16][64];
  int t = threadIdx.x;
  for (int i = t; i < 4096; i += 256) Wf[i] = W[i];
  int base = blockIdx.x * 16;
  for (int i = t; i < 16 * 64; i += 256){
    int r = i >> 6, j = i & 63;
    int nn = base + r;
    xsh[r][j] = (nn < n) ? x[(size_t)nn * xs + xo + j] : 0.f;
  }
  __syncthreads();
  int j = t & 63, w = t >> 6;
  float bj = b[j];
  for (int r = w; r < 16; r += 4){
    int nn = base + r;
    if (nn >= n) continue;
    float acc = bj;
#pragma unroll
    for (int k = 0; k < 64; ++k)
      acc += xsh[r][k] * Wf[k * 64 + j];
    out[(size_t)nn * 64 + j] = acc;
  }
}

// ================= CSR build (per call; ws is re-poisoned) =================
__global__ void k_hist(const int* __restrict__ dst, int* __restrict__ cnt, int E){
  int k = blockIdx.x * 256 + threadIdx.x;
  if (k < E) atomicAdd(cnt + dst[k], 1);
}

// multi-block scan: each block allocates a contiguous range for its 1024-chunk
// via atomicAdd on gbase. Offsets are disjoint but NOT globally monotone ->
// consumers use cnt[] for segment ends (each segment itself is contiguous).
__global__ void k_scan_mb(const int* __restrict__ cnt, int n,
                          int* __restrict__ offs, int* __restrict__ cur,
                          int* __restrict__ gbase){
  __shared__ int wsum[16];
  __shared__ int base_sh;
  int t = threadIdx.x, lane = t & 63, w = t >> 6;
  int i = blockIdx.x * 1024 + t;
  int v = (i < n) ? cnt[i] : 0;
  int x = v;                       // inclusive scan within wave
#pragma unroll
  for (int o = 1; o < 64; o <<= 1){
    int y = __shfl_up(x, o, 64);
    if (lane >= o) x += y;
  }
  if (lane == 63) wsum[w] = x;
  __syncthreads();
  if (t == 0){
    int tot = 0;
    for (int k = 0; k < 16; ++k){ int c = wsum[k]; wsum[k] = tot; tot += c; }
    base_sh = atomicAdd(gbase, tot);
  }
  __syncthreads();
  if (i < n){
    int e = base_sh + wsum[w] + x - v;
    offs[i] = e; cur[i] = e;
  }
}

__global__ void k_csr_fill(const int* __restrict__ src, const int* __restrict__ dst,
                           int* __restrict__ cur, int* __restrict__ csr_src, int E){
  int k = blockIdx.x * 256 + threadIdx.x;
  if (k >= E) return;
  int pos = atomicAdd(cur + dst[k], 1);
  csr_src[pos] = src[k];
}

// ============ fused GATv2 aggregation: one wave per dst node ============
// 4-way unrolled: 4 src rows in flight per iteration (MLP to hide L2 latency)
__global__ void k_gat(const int* __restrict__ offs, const int* __restrict__ cnt,
                      const int* __restrict__ csr_src,
                      const float* __restrict__ fs, const float* __restrict__ fd,
                      const float* __restrict__ attn, const float* __restrict__ bias,
                      float* __restrict__ out, int os, int oo,
                      const float* __restrict__ res, int rs, int ro, int n){
  int d = blockIdx.x * 4 + (threadIdx.x >> 6);
  if (d >= n) return;
  int j = threadIdx.x & 63;
  float fdv = fd[(size_t)d * 64 + j];
  float aj  = attn[j];
  float acc = 0.f, den = 0.f;
  int idx = offs[d], end = idx + cnt[d];
  for (; idx + 4 <= end; idx += 4){
    int s0 = csr_src[idx + 0], s1 = csr_src[idx + 1],
        s2 = csr_src[idx + 2], s3 = csr_src[idx + 3];
    float f0 = fs[(size_t)s0 * 64 + j], f1 = fs[(size_t)s1 * 64 + j],
          f2 = fs[(size_t)s2 * 64 + j], f3 = fs[(size_t)s3 * 64 + j];
    float v0 = f0 + fdv; v0 = (v0 > 0.f ? v0 : 0.2f * v0) * aj;
    float v1 = f1 + fdv; v1 = (v1 > 0.f ? v1 : 0.2f * v1) * aj;
    float v2 = f2 + fdv; v2 = (v2 > 0.f ? v2 : 0.2f * v2) * aj;
    float v3 = f3 + fdv; v3 = (v3 > 0.f ? v3 : 0.2f * v3) * aj;
#pragma unroll
    for (int o = 32; o > 0; o >>= 1){
      v0 += __shfl_xor(v0, o, 64); v1 += __shfl_xor(v1, o, 64);
      v2 += __shfl_xor(v2, o, 64); v3 += __shfl_xor(v3, o, 64);
    }
    float ex0 = __expf(v0), ex1 = __expf(v1), ex2 = __expf(v2), ex3 = __expf(v3);
    acc += ex0 * f0; acc += ex1 * f1; acc += ex2 * f2; acc += ex3 * f3;
    den += (ex0 + ex1) + (ex2 + ex3);
  }
  for (; idx < end; ++idx){
    int s = csr_src[idx];
    float fsv = fs[(size_t)s * 64 + j];
    float v = fsv + fdv;
    v = (v > 0.f ? v : 0.2f * v) * aj;
    float e = wave_sum_all(v);
    float ex = __expf(e);
    acc += ex * fsv;
    den += ex;
  }
  float o = (den > 0.f) ? acc / den : 0.f;   // empty segment -> bias only
  o += bias[j];
  if (res) o += res[(size_t)d * rs + ro + j];
  out[(size_t)d * os + oo + j] = o;
}

// ---- collapse attention-gate MLP: v = W1@W2 (per l,i), c = b1@W2 + b2 ----
__global__ void k_attvec(const float* __restrict__ W1, const float* __restrict__ b1,
                         const float* __restrict__ W2, const float* __restrict__ b2,
                         float* __restrict__ vvec, float* __restrict__ cs){
  int t = threadIdx.x;           // 512 threads: (l*2+i) in [0,4), r in [0,128)
  int li = t >> 7, r = t & 127;
  float acc = 0.f;
  for (int c = 0; c < 128; ++c)
    acc += W1[(size_t)(li * 128 + r) * 128 + c] * W2[li * 128 + c];
  vvec[li * 128 + r] = acc;
  if (r == 0){
    float cacc = b2[li];
    for (int c = 0; c < 128; ++c)
      cacc += b1[li * 128 + c] * W2[li * 128 + c];
    cs[li] = cacc;
  }
}

// ---- gate z-scores + per-block partial sums for BatchNorm ----
__global__ void k_gate_z(const float* __restrict__ hu_all, int l,
                         const float* __restrict__ p, const float* __restrict__ q,
                         const float* __restrict__ vvec, const float* __restrict__ cs,
                         float* __restrict__ z1, float* __restrict__ z2,
                         float* __restrict__ bsums, int n){
  __shared__ float part[4][4];
  int w = threadIdx.x >> 6, j = threadIdx.x & 63;
  int nidx = blockIdx.x * 4 + w;
  float lz1 = 0.f, lz2 = 0.f;
  if (nidx < n){
    const float* v1 = vvec + l * 256;
    const float* v2 = vvec + l * 256 + 128;
    float h  = hu_all[(size_t)nidx * 192 + l * 64 + j];
    float pv = p[(size_t)nidx * 64 + j];
    float qv = q[(size_t)nidx * 64 + j];
    float t1 = wave_sum(h * v1[j] + pv * v1[64 + j]);
    float t2 = wave_sum(h * v2[j] + qv * v2[64 + j]);
    if (j == 0){
      lz1 = t1 + cs[l * 2 + 0];
      lz2 = t2 + cs[l * 2 + 1];
      z1[nidx] = lz1;
      z2[nidx] = lz2;
    }
  }
  if (j == 0){
    part[w][0] = lz1; part[w][1] = lz1 * lz1;
    part[w][2] = lz2; part[w][3] = lz2 * lz2;
  }
  __syncthreads();
  if (threadIdx.x < 4)
    bsums[(size_t)blockIdx.x * 4 + threadIdx.x] =
        part[0][threadIdx.x] + part[1][threadIdx.x] +
        part[2][threadIdx.x] + part[3][threadIdx.x];
}

// ---- BN reduce stage 1: 128 blocks grid-stride over bsums -> gpart[128][4] ----
// (replaces the single-block k_bn_reduce that was 106us: one CU, ~390 dependent
//  HBM-latency loads per thread. Deterministic: fixed per-thread order + tree.)
__global__ void k_bn_part(const float* __restrict__ bsums, int nb,
                          double* __restrict__ gpart){
  __shared__ double sh[256];
  int c = threadIdx.x & 3, r0 = blockIdx.x * 64 + (threadIdx.x >> 2);
  double acc = 0.0;
  for (int i = r0; i < nb; i += gridDim.x * 64)
    acc += (double)bsums[(size_t)i * 4 + c];
  sh[threadIdx.x] = acc;
  __syncthreads();
  for (int s = 128; s >= 4; s >>= 1){
    if (threadIdx.x < s) sh[threadIdx.x] += sh[threadIdx.x + s];
    __syncthreads();
  }
  if (threadIdx.x < 4) gpart[(size_t)blockIdx.x * 4 + threadIdx.x] = sh[threadIdx.x];
}

// ---- BN reduce stage 2: single block over 128 partials -> sums[4] ----
__global__ void k_bn_final(const double* __restrict__ gpart, int nbk,
                           double* __restrict__ sums){
  __shared__ double sh[256];
  int c = threadIdx.x & 3, k0 = threadIdx.x >> 2;
  double acc = 0.0;
  for (int i = k0; i < nbk; i += 64) acc += gpart[(size_t)i * 4 + c];
  sh[threadIdx.x] = acc;
  __syncthreads();
  for (int s = 128; s >= 4; s >>= 1){
    if (threadIdx.x < s) sh[threadIdx.x] += sh[threadIdx.x + s];
    __syncthreads();
  }
  if (threadIdx.x < 4) sums[threadIdx.x] = sh[threadIdx.x];
}

// ---- BN + lrelu(0.01) + softmax gate + residual combine -> hu_all block l+1 ----
__global__ void k_gate_combine(float* __restrict__ hu_all, int l,
                               const float* __restrict__ p, const float* __restrict__ q,
                               const float* __restrict__ z1, const float* __restrict__ z2,
                               const double* __restrict__ sums, int n){
  int idx = blockIdx.x * 256 + threadIdx.x;
  if (idx >= n * 64) return;
  int r = idx >> 6, j = idx & 63;
  double invn = 1.0 / (double)n;
  double mu1 = sums[0] * invn, mu2 = sums[2] * invn;
  float var1 = (float)(sums[1] * invn - mu1 * mu1);
  float var2 = (float)(sums[3] * invn - mu2 * mu2);
  float rs1 = rsqrtf(var1 + 1e-5f), rs2 = rsqrtf(var2 + 1e-5f);
  float a1 = (z1[r] - (float)mu1) * rs1;
  float a2 = (z2[r] - (float)mu2) * rs2;
  a1 = a1 > 0.f ? a1 : 0.01f * a1;
  a2 = a2 > 0.f ? a2 : 0.01f * a2;
  float mx = fmaxf(a1, a2);
  float e1 = __expf(a1 - mx), e2 = __expf(a2 - mx);
  float inv = 1.f / (e1 + e2);
  float out = (e1 * inv) * p[idx] + (e2 * inv) * q[idx]
            + hu_all[(size_t)r * 192 + l * 64 + j];
  hu_all[(size_t)r * 192 + (l + 1) * 64 + j] = out;
}

// ---- final scoring: dot(hu_all[u], hi_all[i]) over 192 dims ----
__global__ void k_score(const int* __restrict__ pu, const int* __restrict__ pi,
                        const int* __restrict__ nu, const int* __restrict__ ni,
                        const float* __restrict__ hu_all, const float* __restrict__ hi_all,
                        float* __restrict__ out, int EP){
  int k = blockIdx.x * 4 + (threadIdx.x >> 6);
  if (k >= 2 * EP) return;
  int j = threadIdx.x & 63;
  int u, i;
  if (k < EP){ u = pu[k]; i = pi[k]; } else { u = nu[k - EP]; i = ni[k - EP]; }
  const float* hu = hu_all + (size_t)u * 192;
  const float* hi = hi_all + (size_t)i * 192;
  float acc = hu[j] * hi[j] + hu[j + 64] * hi[j + 64] + hu[j + 128] * hi[j + 128];
  acc = wave_sum(acc);
  if (j == 0) out[k] = acc;
}

extern "C" void kernel_launch(void* const* d_in, const int* in_sizes, int n_in,
                              void* d_out, int out_size, void* d_ws, size_t ws_size,
                              hipStream_t stream) {
  const int*   rate_src  = (const int*)  d_in[0];
  const int*   rate_dst  = (const int*)  d_in[1];
  const int*   trust_src = (const int*)  d_in[2];
  const int*   trust_dst = (const int*)  d_in[3];
  const int*   pos_u     = (const int*)  d_in[4];
  const int*   pos_i     = (const int*)  d_in[5];
  const int*   neg_u     = (const int*)  d_in[6];
  const int*   neg_i     = (const int*)  d_in[7];
  const float* eu        = (const float*)d_in[8];
  const float* ei        = (const float*)d_in[9];
  const float* rate_W    = (const float*)d_in[10];
  const float* rate_b    = (const float*)d_in[11];
  const float* rate_attn = (const float*)d_in[12];
  const float* rate_bias = (const float*)d_in[13];
  const float* rb_W      = (const float*)d_in[14];
  const float* rb_b      = (const float*)d_in[15];
  const float* rb_attn   = (const float*)d_in[16];
  const float* rb_bias   = (const float*)d_in[17];
  const float* tr_W      = (const float*)d_in[18];
  const float* tr_b      = (const float*)d_in[19];
  const float* tr_attn   = (const float*)d_in[20];
  const float* tr_bias   = (const float*)d_in[21];
  const float* attW1     = (const float*)d_in[22];
  const float* attb1     = (const float*)d_in[23];
  const float* attW2     = (const float*)d_in[24];
  const float* attb2     = (const float*)d_in[25];

  const int ER = in_sizes[0];
  const int ET = in_sizes[2];
  const int EP = in_sizes[4];
  const int NU = in_sizes[8] / 64;
  const int NI = in_sizes[9] / 64;

  // ---- workspace layout: f32 region then int region ----
  float* ws = (float*)d_ws;
  float*  hu_all = ws;                                   // NU*192
  float*  hi_all = hu_all + (size_t)NU * 192;            // NI*192
  float*  p      = hi_all + (size_t)NI * 192;            // NU*64
  float*  q      = p + (size_t)NU * 64;                  // NU*64
  float*  fs     = q + (size_t)NU * 64;                  // NU*64
  float*  fd     = fs + (size_t)NU * 64;                 // NU*64
  float*  z1     = fd + (size_t)NU * 64;                 // NU
  float*  z2     = z1 + NU;                              // NU
  float*  bsums  = z2 + NU;                              // cdiv(NU,4)*4
  float*  vvec   = bsums + (size_t)(((NU + 3) / 4) * 4); // 512
  float*  cs     = vvec + 512;                           // 4
  double* sums   = (double*)(((uintptr_t)(cs + 4) + 15) & ~(uintptr_t)15); // 4
  double* gpart  = sums + 4;           // 128*4 doubles
  int*    iw     = (int*)(gpart + 512);
  // counts (contiguous: one memset) then bases then offs/cur then csr arrays
  int*    cntA   = iw;                 // NI
  int*    cntB   = cntA + NI;          // NU
  int*    cntC   = cntB + NU;          // NU
  int*    gbase  = cntC + NU;          // 4 (3 used)
  int*    offsA  = gbase + 4;          // NI
  int*    curA   = offsA + NI;         // NI
  int*    offsB  = curA + NI;          // NU
  int*    curB   = offsB + NU;         // NU
  int*    offsC  = curB + NU;          // NU
  int*    curC   = offsC + NU;         // NU
  int*    csrA   = curC + NU;          // ER (user srcs, grouped by item)
  int*    csrB   = csrA + ER;          // ER (item srcs, grouped by user)
  int*    csrC   = csrB + ER;          // ET (user srcs, grouped by dst user)

  auto cdiv = [](int a, int b){ return (a + b - 1) / b; };
  const int nbz = cdiv(NU, 4);

  // ---- one-time per call: init state + gate MLP collapse + CSR builds ----
  k_copy_in<<<cdiv(NU * 64, 256), 256, 0, stream>>>(eu, hu_all, NU, 192);
  k_copy_in<<<cdiv(NI * 64, 256), 256, 0, stream>>>(ei, hi_all, NI, 192);
  k_attvec<<<1, 512, 0, stream>>>(attW1, attb1, attW2, attb2, vvec, cs);

  // zero all counts + base cursors in one shot (contiguous)
  hipMemsetAsync(cntA, 0, (size_t)(NI + 2 * NU + 4) * 4, stream);
  k_hist<<<cdiv(ER, 256), 256, 0, stream>>>(rate_dst, cntA, ER);
  k_hist<<<cdiv(ER, 256), 256, 0, stream>>>(rate_src, cntB, ER);
  k_hist<<<cdiv(ET, 256), 256, 0, stream>>>(trust_dst, cntC, ET);
  k_scan_mb<<<cdiv(NI, 1024), 1024, 0, stream>>>(cntA, NI, offsA, curA, gbase + 0);
  k_scan_mb<<<cdiv(NU, 1024), 1024, 0, stream>>>(cntB, NU, offsB, curB, gbase + 1);
  k_scan_mb<<<cdiv(NU, 1024), 1024, 0, stream>>>(cntC, NU, offsC, curC, gbase + 2);
  k_csr_fill<<<cdiv(ER, 256), 256, 0, stream>>>(rate_src, rate_dst, curA, csrA, ER);
  k_csr_fill<<<cdiv(ER, 256), 256, 0, stream>>>(rate_dst, rate_src, curB, csrB, ER);
  k_csr_fill<<<cdiv(ET, 256), 256, 0, stream>>>(trust_src, trust_dst, curC, csrC, ET);

  for (int l = 0; l < 2; ++l){
    // ---------- rate GAT: users -> items, into hi_all block l+1 (+bias+residual) ----------
    k_linear<<<cdiv(NU, 16), 256, 0, stream>>>(hu_all, 192, l * 64,
        rate_W + (size_t)(l * 2 + 0) * 4096, rate_b + (l * 2 + 0) * 64, fs, NU);
    k_linear<<<cdiv(NI, 16), 256, 0, stream>>>(hi_all, 192, l * 64,
        rate_W + (size_t)(l * 2 + 1) * 4096, rate_b + (l * 2 + 1) * 64, fd, NI);
    k_gat<<<cdiv(NI, 4), 256, 0, stream>>>(offsA, cntA, csrA, fs, fd,
        rate_attn + l * 64, rate_bias + l * 64,
        hi_all, 192, (l + 1) * 64, hi_all, 192, l * 64, NI);

    // ---------- rated-by GAT: items -> users, result q ----------
    k_linear<<<cdiv(NI, 16), 256, 0, stream>>>(hi_all, 192, l * 64,
        rb_W + (size_t)(l * 2 + 0) * 4096, rb_b + (l * 2 + 0) * 64, fs, NI);
    k_linear<<<cdiv(NU, 16), 256, 0, stream>>>(hu_all, 192, l * 64,
        rb_W + (size_t)(l * 2 + 1) * 4096, rb_b + (l * 2 + 1) * 64, fd, NU);
    k_gat<<<cdiv(NU, 4), 256, 0, stream>>>(offsB, cntB, csrB, fs, fd,
        rb_attn + l * 64, rb_bias + l * 64,
        q, 64, 0, (const float*)nullptr, 0, 0, NU);

    // ---------- trust GAT: users -> users, result p ----------
    k_linear<<<cdiv(NU, 16), 256, 0, stream>>>(hu_all, 192, l * 64,
        tr_W + (size_t)(l * 2 + 0) * 4096, tr_b + (l * 2 + 0) * 64, fs, NU);
    k_linear<<<cdiv(NU, 16), 256, 0, stream>>>(hu_all, 192, l * 64,
        tr_W + (size_t)(l * 2 + 1) * 4096, tr_b + (l * 2 + 1) * 64, fd, NU);
    k_gat<<<cdiv(NU, 4), 256, 0, stream>>>(offsC, cntC, csrC, fs, fd,
        tr_attn + l * 64, tr_bias + l * 64,
        p, 64, 0, (const float*)nullptr, 0, 0, NU);

    // ---------- attention gate + combine -> hu_all block l+1 ----------
    k_gate_z<<<nbz, 256, 0, stream>>>(hu_all, l, p, q, vvec, cs, z1, z2, bsums, NU);
    k_bn_part<<<128, 256, 0, stream>>>(bsums, nbz, gpart);
    k_bn_final<<<1, 256, 0, stream>>>(gpart, 128, sums);
    k_gate_combine<<<cdiv(NU * 64, 256), 256, 0, stream>>>(hu_all, l, p, q, z1, z2, sums, NU);
  }

  // ---------- final scoring ----------
  k_score<<<cdiv(2 * EP, 4), 256, 0, stream>>>(pos_u, pos_i, neg_u, neg_i,
      hu_all, hi_all, (float*)d_out, EP);
}